// Round 1
// baseline (3033.019 us; speedup 1.0000x reference)
//
#include <hip/hip_runtime.h>
#include <hip/hip_bf16.h>

#define NN 100000
#define NE 1600000
#define DD 128
#define DFF 256
#define BN_EPS 1e-5f
#define NND ((size_t)NN * DD)

typedef __attribute__((ext_vector_type(8))) short short8;
typedef __attribute__((ext_vector_type(4))) float f32x4;

static __device__ __forceinline__ unsigned short f2bf(float f) {
  union { float f; unsigned u; } v; v.f = f;
  unsigned r = v.u + 0x7fffu + ((v.u >> 16) & 1u);
  return (unsigned short)(r >> 16);
}
static __device__ __forceinline__ float bf2f(unsigned short h) {
  union { unsigned u; float f; } v; v.u = ((unsigned)h) << 16;
  return v.f;
}

// ---------------- weight transpose+convert: dst[c*K+k] = bf16(src[k*Nc+c]) ----
__global__ void k_cvt_t(const float* __restrict__ s, unsigned short* __restrict__ d,
                        int K, int Nc) {
  int i = blockIdx.x * 256 + threadIdx.x;
  if (i >= K * Nc) return;
  int c = i % Nc, k = i / Nc;
  d[c * K + k] = f2bf(s[(size_t)k * Nc + c]);
}

// ---------------- edge scatter: agg[dst] += relu(x[src] + ea[e]) -------------
__global__ __launch_bounds__(256) void k_edge(const float* __restrict__ x,
    const float* __restrict__ ea, const int* __restrict__ ei,
    float* __restrict__ agg) {
  unsigned gid = blockIdx.x * 256u + threadIdx.x;
  unsigned e = gid >> 5, q = gid & 31;
  if (e >= NE) return;
  int s = ei[e], d = ei[NE + e];
  f32x4 xv = *(reinterpret_cast<const f32x4*>(x + (size_t)s * DD) + q);
  f32x4 ev = *(reinterpret_cast<const f32x4*>(ea + (size_t)e * DD) + q);
  float* ap = agg + (size_t)d * DD + q * 4;
#pragma unroll
  for (int c = 0; c < 4; ++c) {
    float m = xv[c] + ev[c];
    if (m > 0.f) atomicAdd(ap + c, m);
  }
}

// ---------------- h0bf = bf16(x + agg) ---------------------------------------
__global__ __launch_bounds__(256) void k_prep(const float* __restrict__ x,
    const float* __restrict__ agg, unsigned short* __restrict__ h0) {
  size_t base = ((size_t)blockIdx.x * 256u + threadIdx.x) * 8;
  if (base >= NND) return;
  const f32x4* xp = reinterpret_cast<const f32x4*>(x + base);
  const f32x4* ap = reinterpret_cast<const f32x4*>(agg + base);
  f32x4 a0 = xp[0] + ap[0], a1 = xp[1] + ap[1];
  short8 o;
#pragma unroll
  for (int j = 0; j < 4; ++j) o[j] = (short)f2bf(a0[j]);
#pragma unroll
  for (int j = 0; j < 4; ++j) o[4 + j] = (short)f2bf(a1[j]);
  *reinterpret_cast<short8*>(h0 + base) = o;
}

// ---------------- GEMM1: r1 = relu(h0 @ W1 + b1) -> bf16  (K=128,N=128) ------
__global__ __launch_bounds__(256) void k_gemm1(const unsigned short* __restrict__ A,
    const unsigned short* __restrict__ WT, const float* __restrict__ bias,
    unsigned short* __restrict__ O) {
  int lane = threadIdx.x & 63, w = threadIdx.x >> 6;
  int tile = blockIdx.x * 4 + w;
  if (tile >= NN / 16) return;
  int l15 = lane & 15, g = lane >> 4;
  int row0 = tile * 16;
  f32x4 acc[8];
#pragma unroll
  for (int ct = 0; ct < 8; ++ct) {
    float b = bias[ct * 16 + l15];
    acc[ct] = (f32x4){b, b, b, b};
  }
  short8 a[4];
#pragma unroll
  for (int kt = 0; kt < 4; ++kt)
    a[kt] = *reinterpret_cast<const short8*>(A + (size_t)(row0 + l15) * DD + kt * 32 + g * 8);
#pragma unroll
  for (int kt = 0; kt < 4; ++kt) {
    int k0 = kt * 32 + g * 8;
#pragma unroll
    for (int ct = 0; ct < 8; ++ct) {
      int c = ct * 16 + l15;
      short8 b = *reinterpret_cast<const short8*>(WT + (size_t)c * DD + k0);
      acc[ct] = __builtin_amdgcn_mfma_f32_16x16x32_bf16(a[kt], b, acc[ct], 0, 0, 0);
    }
  }
#pragma unroll
  for (int ct = 0; ct < 8; ++ct) {
    int c = ct * 16 + l15;
#pragma unroll
    for (int r = 0; r < 4; ++r) {
      int row = row0 + g * 4 + r;
      float v = acc[ct][r];
      v = v > 0.f ? v : 0.f;
      O[(size_t)row * DD + c] = f2bf(v);
    }
  }
}

// ---------------- GEMM2: hpre1 = x + relu(r1 @ W2 + b2) -> f32 ---------------
__global__ __launch_bounds__(256) void k_gemm2(const unsigned short* __restrict__ A,
    const unsigned short* __restrict__ WT, const float* __restrict__ bias,
    const float* __restrict__ x, float* __restrict__ O) {
  int lane = threadIdx.x & 63, w = threadIdx.x >> 6;
  int tile = blockIdx.x * 4 + w;
  if (tile >= NN / 16) return;
  int l15 = lane & 15, g = lane >> 4;
  int row0 = tile * 16;
  f32x4 acc[8];
#pragma unroll
  for (int ct = 0; ct < 8; ++ct) {
    float b = bias[ct * 16 + l15];
    acc[ct] = (f32x4){b, b, b, b};
  }
  short8 a[4];
#pragma unroll
  for (int kt = 0; kt < 4; ++kt)
    a[kt] = *reinterpret_cast<const short8*>(A + (size_t)(row0 + l15) * DD + kt * 32 + g * 8);
#pragma unroll
  for (int kt = 0; kt < 4; ++kt) {
    int k0 = kt * 32 + g * 8;
#pragma unroll
    for (int ct = 0; ct < 8; ++ct) {
      int c = ct * 16 + l15;
      short8 b = *reinterpret_cast<const short8*>(WT + (size_t)c * DD + k0);
      acc[ct] = __builtin_amdgcn_mfma_f32_16x16x32_bf16(a[kt], b, acc[ct], 0, 0, 0);
    }
  }
#pragma unroll
  for (int ct = 0; ct < 8; ++ct) {
    int c = ct * 16 + l15;
#pragma unroll
    for (int r = 0; r < 4; ++r) {
      int row = row0 + g * 4 + r;
      float v = acc[ct][r];
      v = v > 0.f ? v : 0.f;
      O[(size_t)row * DD + c] = x[(size_t)row * DD + c] + v;
    }
  }
}

// ---------------- GEMM3: f1 = relu(h1 @ FFW1 + fb1) -> bf16 (K=128,N=256) ----
__global__ __launch_bounds__(256) void k_gemm3(const unsigned short* __restrict__ A,
    const unsigned short* __restrict__ WT, const float* __restrict__ bias,
    unsigned short* __restrict__ O) {
  int lane = threadIdx.x & 63, w = threadIdx.x >> 6;
  int colhalf = w & 1;
  int tile = blockIdx.x * 2 + (w >> 1);
  if (tile >= NN / 16) return;
  int l15 = lane & 15, g = lane >> 4;
  int row0 = tile * 16;
  f32x4 acc[8];
#pragma unroll
  for (int ct = 0; ct < 8; ++ct) {
    float b = bias[colhalf * 128 + ct * 16 + l15];
    acc[ct] = (f32x4){b, b, b, b};
  }
  short8 a[4];
#pragma unroll
  for (int kt = 0; kt < 4; ++kt)
    a[kt] = *reinterpret_cast<const short8*>(A + (size_t)(row0 + l15) * DD + kt * 32 + g * 8);
#pragma unroll
  for (int kt = 0; kt < 4; ++kt) {
    int k0 = kt * 32 + g * 8;
#pragma unroll
    for (int ct = 0; ct < 8; ++ct) {
      int c = colhalf * 128 + ct * 16 + l15;
      short8 b = *reinterpret_cast<const short8*>(WT + (size_t)c * DD + k0);
      acc[ct] = __builtin_amdgcn_mfma_f32_16x16x32_bf16(a[kt], b, acc[ct], 0, 0, 0);
    }
  }
#pragma unroll
  for (int ct = 0; ct < 8; ++ct) {
    int c = colhalf * 128 + ct * 16 + l15;
#pragma unroll
    for (int r = 0; r < 4; ++r) {
      int row = row0 + g * 4 + r;
      float v = acc[ct][r];
      v = v > 0.f ? v : 0.f;
      O[(size_t)row * DFF + c] = f2bf(v);
    }
  }
}

// ---------------- GEMM4: out = h1 + f1 @ FFW2 + fb2 -> f32 (K=256,N=128) -----
__global__ __launch_bounds__(256) void k_gemm4(const unsigned short* __restrict__ A,
    const unsigned short* __restrict__ WT, const float* __restrict__ bias,
    const unsigned short* __restrict__ h1, float* __restrict__ O) {
  int lane = threadIdx.x & 63, w = threadIdx.x >> 6;
  int tile = blockIdx.x * 4 + w;
  if (tile >= NN / 16) return;
  int l15 = lane & 15, g = lane >> 4;
  int row0 = tile * 16;
  f32x4 acc[8];
#pragma unroll
  for (int ct = 0; ct < 8; ++ct) {
    float b = bias[ct * 16 + l15];
    acc[ct] = (f32x4){b, b, b, b};
  }
  short8 a[8];
#pragma unroll
  for (int kt = 0; kt < 8; ++kt)
    a[kt] = *reinterpret_cast<const short8*>(A + (size_t)(row0 + l15) * DFF + kt * 32 + g * 8);
#pragma unroll 2
  for (int kt = 0; kt < 8; ++kt) {
    int k0 = kt * 32 + g * 8;
#pragma unroll
    for (int ct = 0; ct < 8; ++ct) {
      int c = ct * 16 + l15;
      short8 b = *reinterpret_cast<const short8*>(WT + (size_t)c * DFF + k0);
      acc[ct] = __builtin_amdgcn_mfma_f32_16x16x32_bf16(a[kt], b, acc[ct], 0, 0, 0);
    }
  }
#pragma unroll
  for (int ct = 0; ct < 8; ++ct) {
    int c = ct * 16 + l15;
#pragma unroll
    for (int r = 0; r < 4; ++r) {
      int row = row0 + g * 4 + r;
      O[(size_t)row * DD + c] = acc[ct][r] + bf2f(h1[(size_t)row * DD + c]);
    }
  }
}

// ---------------- column stats: out[c] += sum, out[128+c] += sumsq -----------
__global__ __launch_bounds__(256) void k_stats(const float* __restrict__ h,
                                               float* __restrict__ out) {
  int c = threadIdx.x & 127, half = threadIdx.x >> 7;
  int row0 = blockIdx.x * 250;
  float s = 0.f, q = 0.f;
  for (int r = half; r < 250; r += 2) {
    float v = h[(size_t)(row0 + r) * DD + c];
    s += v; q += v * v;
  }
  __shared__ float ls[256], lq[256];
  ls[threadIdx.x] = s; lq[threadIdx.x] = q;
  __syncthreads();
  if (threadIdx.x < 128) {
    s = ls[threadIdx.x] + ls[threadIdx.x + 128];
    q = lq[threadIdx.x] + lq[threadIdx.x + 128];
    atomicAdd(&out[c], s);
    atomicAdd(&out[128 + c], q);
  }
}

// ---------------- BN finalize: par[c]=scale, par[128+c]=shift ----------------
__global__ void k_bnfin(const float* __restrict__ st, const float* __restrict__ gm,
                        const float* __restrict__ bt, float* __restrict__ par) {
  int c = threadIdx.x;
  float mean = st[c] * (1.f / NN);
  float var = st[128 + c] * (1.f / NN) - mean * mean;
  float sc = gm[c] * rsqrtf(var + BN_EPS);
  par[c] = sc;
  par[128 + c] = bt[c] - mean * sc;
}

// ---------------- BN apply -> bf16 -------------------------------------------
__global__ __launch_bounds__(256) void k_bnapply_bf(const float* __restrict__ h,
    const float* __restrict__ par, unsigned short* __restrict__ o) {
  size_t base = ((size_t)blockIdx.x * 256u + threadIdx.x) * 8;
  if (base >= NND) return;
  int c0 = (int)(base & 127);
  const f32x4* hp = reinterpret_cast<const f32x4*>(h + base);
  f32x4 h0 = hp[0], h1 = hp[1];
  short8 o8;
#pragma unroll
  for (int j = 0; j < 4; ++j)
    o8[j] = (short)f2bf(par[c0 + j] * h0[j] + par[128 + c0 + j]);
#pragma unroll
  for (int j = 0; j < 4; ++j)
    o8[4 + j] = (short)f2bf(par[c0 + 4 + j] * h1[j] + par[128 + c0 + 4 + j]);
  *reinterpret_cast<short8*>(o + base) = o8;
}

// ---------------- BN apply in-place f32 --------------------------------------
__global__ __launch_bounds__(256) void k_bnapply_f32(float* __restrict__ h,
                                                     const float* __restrict__ par) {
  size_t base = ((size_t)blockIdx.x * 256u + threadIdx.x) * 4;
  if (base >= NND) return;
  int c0 = (int)(base & 127);
  f32x4* hp = reinterpret_cast<f32x4*>(h + base);
  f32x4 v = *hp;
#pragma unroll
  for (int j = 0; j < 4; ++j) v[j] = par[c0 + j] * v[j] + par[128 + c0 + j];
  *hp = v;
}

extern "C" void kernel_launch(void* const* d_in, const int* in_sizes, int n_in,
                              void* d_out, int out_size, void* d_ws, size_t ws_size,
                              hipStream_t stream) {
  const float* x    = (const float*)d_in[0];
  const float* ea   = (const float*)d_in[1];
  const float* w1g  = (const float*)d_in[2];
  const float* b1g  = (const float*)d_in[3];
  const float* w2g  = (const float*)d_in[4];
  const float* b2g  = (const float*)d_in[5];
  const float* bn1g = (const float*)d_in[6];
  const float* bn1b = (const float*)d_in[7];
  const float* ffw1 = (const float*)d_in[8];
  const float* ffb1 = (const float*)d_in[9];
  const float* ffw2 = (const float*)d_in[10];
  const float* ffb2 = (const float*)d_in[11];
  const float* bn2g = (const float*)d_in[12];
  const float* bn2b = (const float*)d_in[13];
  const int*   eidx = (const int*)d_in[14];
  float* out = (float*)d_out;

  char* ws = (char*)d_ws;
  float* fbuf          = (float*)(ws);                    // 51.2MB: agg, then hpre1
  unsigned short* hbf  = (unsigned short*)(ws + 51200000);// 25.6MB: h0bf, then h1bf
  unsigned short* r1bf = (unsigned short*)(ws + 76800000);// 25.6MB
  unsigned short* f1bf = (unsigned short*)(ws + 102400000);// 51.2MB
  unsigned short* w1t  = (unsigned short*)(ws + 153600000);
  unsigned short* w2t  = w1t + 16384;
  unsigned short* fw1t = w2t + 16384;   // 32768 elems
  unsigned short* fw2t = fw1t + 32768;  // 32768 elems
  float* stats = (float*)(ws + 153600000 + 196608);       // 512 f32 (BN1 then BN2)
  float* par   = stats + 512;                              // 512 f32

  hipMemsetAsync(fbuf, 0, NND * 4, stream);
  hipMemsetAsync(stats, 0, 512 * 4, stream);

  k_cvt_t<<<64, 256, 0, stream>>>(w1g, w1t, 128, 128);
  k_cvt_t<<<64, 256, 0, stream>>>(w2g, w2t, 128, 128);
  k_cvt_t<<<128, 256, 0, stream>>>(ffw1, fw1t, 128, 256);
  k_cvt_t<<<128, 256, 0, stream>>>(ffw2, fw2t, 256, 128);

  k_edge<<<200000, 256, 0, stream>>>(x, ea, eidx, fbuf);
  k_prep<<<6250, 256, 0, stream>>>(x, fbuf, hbf);

  k_gemm1<<<1563, 256, 0, stream>>>(hbf, w1t, b1g, r1bf);
  k_gemm2<<<1563, 256, 0, stream>>>(r1bf, w2t, b2g, x, fbuf);   // fbuf = hpre1

  k_stats<<<400, 256, 0, stream>>>(fbuf, stats);
  k_bnfin<<<1, 128, 0, stream>>>(stats, bn1g, bn1b, par);
  k_bnapply_bf<<<6250, 256, 0, stream>>>(fbuf, par, hbf);       // hbf = h1 (bf16)

  k_gemm3<<<3125, 256, 0, stream>>>(hbf, fw1t, ffb1, f1bf);
  k_gemm4<<<1563, 256, 0, stream>>>(f1bf, fw2t, ffb2, hbf, out);

  k_stats<<<400, 256, 0, stream>>>(out, stats + 256);
  k_bnfin<<<1, 128, 0, stream>>>(stats + 256, bn2g, bn2b, par + 256);
  k_bnapply_f32<<<12500, 256, 0, stream>>>(out, par + 256);
}

// Round 2
// 978.813 us; speedup vs baseline: 3.0987x; 3.0987x over previous
//
#include <hip/hip_runtime.h>
#include <hip/hip_bf16.h>

#define NN 100000
#define NE 1600000
#define DD 128
#define DFF 256
#define BN_EPS 1e-5f
#define NND ((size_t)NN * DD)
#define NB_SCAN 391  // ceil(NN/256)

typedef __attribute__((ext_vector_type(8))) short short8;
typedef __attribute__((ext_vector_type(4))) float f32x4;

static __device__ __forceinline__ unsigned short f2bf(float f) {
  union { float f; unsigned u; } v; v.f = f;
  unsigned r = v.u + 0x7fffu + ((v.u >> 16) & 1u);
  return (unsigned short)(r >> 16);
}
static __device__ __forceinline__ float bf2f(unsigned short h) {
  union { unsigned u; float f; } v; v.u = ((unsigned)h) << 16;
  return v.f;
}

// ---------------- weight transpose+convert: dst[c*K+k] = bf16(src[k*Nc+c]) ----
__global__ void k_cvt_t(const float* __restrict__ s, unsigned short* __restrict__ d,
                        int K, int Nc) {
  int i = blockIdx.x * 256 + threadIdx.x;
  if (i >= K * Nc) return;
  int c = i % Nc, k = i / Nc;
  d[c * K + k] = f2bf(s[(size_t)k * Nc + c]);
}

// ---------------- histogram: cnt[dst]++ --------------------------------------
__global__ __launch_bounds__(256) void k_hist(const int* __restrict__ ei,
                                              int* __restrict__ cnt) {
  int e = blockIdx.x * 256 + threadIdx.x;
  if (e >= NE) return;
  atomicAdd(&cnt[ei[NE + e]], 1);
}

// ---------------- scan stage 1: per-block sums -------------------------------
__global__ __launch_bounds__(256) void k_scan1(const int* __restrict__ cnt,
                                               int* __restrict__ bsum) {
  __shared__ int sh[256];
  int n = blockIdx.x * 256 + threadIdx.x;
  sh[threadIdx.x] = (n < NN) ? cnt[n] : 0;
  __syncthreads();
  for (int off = 128; off > 0; off >>= 1) {
    if (threadIdx.x < off) sh[threadIdx.x] += sh[threadIdx.x + off];
    __syncthreads();
  }
  if (threadIdx.x == 0) bsum[blockIdx.x] = sh[0];
}

// ---------------- scan stage 2: scan block sums (single block) ---------------
__global__ __launch_bounds__(512) void k_scan2(const int* __restrict__ bsum,
                                               int* __restrict__ bpre,
                                               int* __restrict__ rs) {
  __shared__ int sh[512];
  int t = threadIdx.x;
  int v = (t < NB_SCAN) ? bsum[t] : 0;
  sh[t] = v;
  __syncthreads();
  for (int off = 1; off < 512; off <<= 1) {
    int u = (t >= off) ? sh[t - off] : 0;
    __syncthreads();
    sh[t] += u;
    __syncthreads();
  }
  if (t < NB_SCAN) bpre[t] = sh[t] - v;        // exclusive
  if (t == NB_SCAN - 1) rs[NN] = sh[t];        // total = NE
}

// ---------------- scan stage 3: in-place exclusive prefix + cursor init ------
__global__ __launch_bounds__(256) void k_scan3(int* __restrict__ rs,
                                               const int* __restrict__ bpre,
                                               int* __restrict__ cursor) {
  __shared__ int sh[256];
  int n = blockIdx.x * 256 + threadIdx.x;
  int t = threadIdx.x;
  int v = (n < NN) ? rs[n] : 0;
  sh[t] = v;
  __syncthreads();
  for (int off = 1; off < 256; off <<= 1) {
    int u = (t >= off) ? sh[t - off] : 0;
    __syncthreads();
    sh[t] += u;
    __syncthreads();
  }
  if (n < NN) {
    int ex = bpre[blockIdx.x] + sh[t] - v;
    rs[n] = ex;
    cursor[n] = ex;
  }
}

// ---------------- scatter edge ids into dst-sorted order ---------------------
__global__ __launch_bounds__(256) void k_scatter(const int* __restrict__ ei,
                                                 int* __restrict__ cursor,
                                                 int* __restrict__ elist) {
  int e = blockIdx.x * 256 + threadIdx.x;
  if (e >= NE) return;
  int d = ei[NE + e];
  int p = atomicAdd(&cursor[d], 1);
  elist[p] = e;
}

// ---------------- gather: h0bf[n] = bf16(x[n] + sum relu(x[src]+ea[e])) ------
__global__ __launch_bounds__(256) void k_gather(const float* __restrict__ x,
    const float* __restrict__ ea, const int* __restrict__ ei,
    const int* __restrict__ rs, const int* __restrict__ elist,
    unsigned short* __restrict__ h0) {
  int n = blockIdx.x * 8 + (threadIdx.x >> 5);
  int q = threadIdx.x & 31;
  int beg = rs[n], end = rs[n + 1];
  f32x4 acc = (f32x4){0.f, 0.f, 0.f, 0.f};
  int e = 0, s = 0;
  if (beg < end) { e = elist[beg]; s = ei[e]; }
  for (int i = beg; i < end; ++i) {
    int e2 = 0, s2 = 0;
    if (i + 1 < end) { e2 = elist[i + 1]; s2 = ei[e2]; }  // prefetch index chain
    f32x4 xv = *(reinterpret_cast<const f32x4*>(x + (size_t)s * DD) + q);
    f32x4 ev = *(reinterpret_cast<const f32x4*>(ea + (size_t)e * DD) + q);
#pragma unroll
    for (int c = 0; c < 4; ++c) {
      float m = xv[c] + ev[c];
      acc[c] += (m > 0.f) ? m : 0.f;
    }
    e = e2; s = s2;
  }
  f32x4 xn = *(reinterpret_cast<const f32x4*>(x + (size_t)n * DD) + q);
  union { unsigned short us[4]; unsigned long long u; } pk;
#pragma unroll
  for (int c = 0; c < 4; ++c) pk.us[c] = f2bf(xn[c] + acc[c]);
  *reinterpret_cast<unsigned long long*>(h0 + (size_t)n * DD + q * 4) = pk.u;
}

// ---------------- GEMM1: r1 = relu(h0 @ W1 + b1) -> bf16  (K=128,N=128) ------
__global__ __launch_bounds__(256) void k_gemm1(const unsigned short* __restrict__ A,
    const unsigned short* __restrict__ WT, const float* __restrict__ bias,
    unsigned short* __restrict__ O) {
  int lane = threadIdx.x & 63, w = threadIdx.x >> 6;
  int tile = blockIdx.x * 4 + w;
  if (tile >= NN / 16) return;
  int l15 = lane & 15, g = lane >> 4;
  int row0 = tile * 16;
  f32x4 acc[8];
#pragma unroll
  for (int ct = 0; ct < 8; ++ct) {
    float b = bias[ct * 16 + l15];
    acc[ct] = (f32x4){b, b, b, b};
  }
  short8 a[4];
#pragma unroll
  for (int kt = 0; kt < 4; ++kt)
    a[kt] = *reinterpret_cast<const short8*>(A + (size_t)(row0 + l15) * DD + kt * 32 + g * 8);
#pragma unroll
  for (int kt = 0; kt < 4; ++kt) {
    int k0 = kt * 32 + g * 8;
#pragma unroll
    for (int ct = 0; ct < 8; ++ct) {
      int c = ct * 16 + l15;
      short8 b = *reinterpret_cast<const short8*>(WT + (size_t)c * DD + k0);
      acc[ct] = __builtin_amdgcn_mfma_f32_16x16x32_bf16(a[kt], b, acc[ct], 0, 0, 0);
    }
  }
#pragma unroll
  for (int ct = 0; ct < 8; ++ct) {
    int c = ct * 16 + l15;
#pragma unroll
    for (int r = 0; r < 4; ++r) {
      int row = row0 + g * 4 + r;
      float v = acc[ct][r];
      v = v > 0.f ? v : 0.f;
      O[(size_t)row * DD + c] = f2bf(v);
    }
  }
}

// ---------------- GEMM2: hpre1 = x + relu(r1 @ W2 + b2) -> f32 ---------------
__global__ __launch_bounds__(256) void k_gemm2(const unsigned short* __restrict__ A,
    const unsigned short* __restrict__ WT, const float* __restrict__ bias,
    const float* __restrict__ x, float* __restrict__ O) {
  int lane = threadIdx.x & 63, w = threadIdx.x >> 6;
  int tile = blockIdx.x * 4 + w;
  if (tile >= NN / 16) return;
  int l15 = lane & 15, g = lane >> 4;
  int row0 = tile * 16;
  f32x4 acc[8];
#pragma unroll
  for (int ct = 0; ct < 8; ++ct) {
    float b = bias[ct * 16 + l15];
    acc[ct] = (f32x4){b, b, b, b};
  }
  short8 a[4];
#pragma unroll
  for (int kt = 0; kt < 4; ++kt)
    a[kt] = *reinterpret_cast<const short8*>(A + (size_t)(row0 + l15) * DD + kt * 32 + g * 8);
#pragma unroll
  for (int kt = 0; kt < 4; ++kt) {
    int k0 = kt * 32 + g * 8;
#pragma unroll
    for (int ct = 0; ct < 8; ++ct) {
      int c = ct * 16 + l15;
      short8 b = *reinterpret_cast<const short8*>(WT + (size_t)c * DD + k0);
      acc[ct] = __builtin_amdgcn_mfma_f32_16x16x32_bf16(a[kt], b, acc[ct], 0, 0, 0);
    }
  }
#pragma unroll
  for (int ct = 0; ct < 8; ++ct) {
    int c = ct * 16 + l15;
#pragma unroll
    for (int r = 0; r < 4; ++r) {
      int row = row0 + g * 4 + r;
      float v = acc[ct][r];
      v = v > 0.f ? v : 0.f;
      O[(size_t)row * DD + c] = x[(size_t)row * DD + c] + v;
    }
  }
}

// ---------------- GEMM3: f1 = relu(h1 @ FFW1 + fb1) -> bf16 (K=128,N=256) ----
__global__ __launch_bounds__(256) void k_gemm3(const unsigned short* __restrict__ A,
    const unsigned short* __restrict__ WT, const float* __restrict__ bias,
    unsigned short* __restrict__ O) {
  int lane = threadIdx.x & 63, w = threadIdx.x >> 6;
  int colhalf = w & 1;
  int tile = blockIdx.x * 2 + (w >> 1);
  if (tile >= NN / 16) return;
  int l15 = lane & 15, g = lane >> 4;
  int row0 = tile * 16;
  f32x4 acc[8];
#pragma unroll
  for (int ct = 0; ct < 8; ++ct) {
    float b = bias[colhalf * 128 + ct * 16 + l15];
    acc[ct] = (f32x4){b, b, b, b};
  }
  short8 a[4];
#pragma unroll
  for (int kt = 0; kt < 4; ++kt)
    a[kt] = *reinterpret_cast<const short8*>(A + (size_t)(row0 + l15) * DD + kt * 32 + g * 8);
#pragma unroll
  for (int kt = 0; kt < 4; ++kt) {
    int k0 = kt * 32 + g * 8;
#pragma unroll
    for (int ct = 0; ct < 8; ++ct) {
      int c = colhalf * 128 + ct * 16 + l15;
      short8 b = *reinterpret_cast<const short8*>(WT + (size_t)c * DD + k0);
      acc[ct] = __builtin_amdgcn_mfma_f32_16x16x32_bf16(a[kt], b, acc[ct], 0, 0, 0);
    }
  }
#pragma unroll
  for (int ct = 0; ct < 8; ++ct) {
    int c = colhalf * 128 + ct * 16 + l15;
#pragma unroll
    for (int r = 0; r < 4; ++r) {
      int row = row0 + g * 4 + r;
      float v = acc[ct][r];
      v = v > 0.f ? v : 0.f;
      O[(size_t)row * DFF + c] = f2bf(v);
    }
  }
}

// ---------------- GEMM4: out = h1 + f1 @ FFW2 + fb2 -> f32 (K=256,N=128) -----
__global__ __launch_bounds__(256) void k_gemm4(const unsigned short* __restrict__ A,
    const unsigned short* __restrict__ WT, const float* __restrict__ bias,
    const unsigned short* __restrict__ h1, float* __restrict__ O) {
  int lane = threadIdx.x & 63, w = threadIdx.x >> 6;
  int tile = blockIdx.x * 4 + w;
  if (tile >= NN / 16) return;
  int l15 = lane & 15, g = lane >> 4;
  int row0 = tile * 16;
  f32x4 acc[8];
#pragma unroll
  for (int ct = 0; ct < 8; ++ct) {
    float b = bias[ct * 16 + l15];
    acc[ct] = (f32x4){b, b, b, b};
  }
  short8 a[8];
#pragma unroll
  for (int kt = 0; kt < 8; ++kt)
    a[kt] = *reinterpret_cast<const short8*>(A + (size_t)(row0 + l15) * DFF + kt * 32 + g * 8);
#pragma unroll 2
  for (int kt = 0; kt < 8; ++kt) {
    int k0 = kt * 32 + g * 8;
#pragma unroll
    for (int ct = 0; ct < 8; ++ct) {
      int c = ct * 16 + l15;
      short8 b = *reinterpret_cast<const short8*>(WT + (size_t)c * DFF + k0);
      acc[ct] = __builtin_amdgcn_mfma_f32_16x16x32_bf16(a[kt], b, acc[ct], 0, 0, 0);
    }
  }
#pragma unroll
  for (int ct = 0; ct < 8; ++ct) {
    int c = ct * 16 + l15;
#pragma unroll
    for (int r = 0; r < 4; ++r) {
      int row = row0 + g * 4 + r;
      O[(size_t)row * DD + c] = acc[ct][r] + bf2f(h1[(size_t)row * DD + c]);
    }
  }
}

// ---------------- column stats: out[c] += sum, out[128+c] += sumsq -----------
__global__ __launch_bounds__(256) void k_stats(const float* __restrict__ h,
                                               float* __restrict__ out) {
  int c = threadIdx.x & 127, half = threadIdx.x >> 7;
  int row0 = blockIdx.x * 250;
  float s = 0.f, q = 0.f;
  for (int r = half; r < 250; r += 2) {
    float v = h[(size_t)(row0 + r) * DD + c];
    s += v; q += v * v;
  }
  __shared__ float ls[256], lq[256];
  ls[threadIdx.x] = s; lq[threadIdx.x] = q;
  __syncthreads();
  if (threadIdx.x < 128) {
    s = ls[threadIdx.x] + ls[threadIdx.x + 128];
    q = lq[threadIdx.x] + lq[threadIdx.x + 128];
    atomicAdd(&out[c], s);
    atomicAdd(&out[128 + c], q);
  }
}

// ---------------- BN finalize: par[c]=scale, par[128+c]=shift ----------------
__global__ void k_bnfin(const float* __restrict__ st, const float* __restrict__ gm,
                        const float* __restrict__ bt, float* __restrict__ par) {
  int c = threadIdx.x;
  float mean = st[c] * (1.f / NN);
  float var = st[128 + c] * (1.f / NN) - mean * mean;
  float sc = gm[c] * rsqrtf(var + BN_EPS);
  par[c] = sc;
  par[128 + c] = bt[c] - mean * sc;
}

// ---------------- BN apply -> bf16 -------------------------------------------
__global__ __launch_bounds__(256) void k_bnapply_bf(const float* __restrict__ h,
    const float* __restrict__ par, unsigned short* __restrict__ o) {
  size_t base = ((size_t)blockIdx.x * 256u + threadIdx.x) * 8;
  if (base >= NND) return;
  int c0 = (int)(base & 127);
  const f32x4* hp = reinterpret_cast<const f32x4*>(h + base);
  f32x4 h0 = hp[0], h1 = hp[1];
  short8 o8;
#pragma unroll
  for (int j = 0; j < 4; ++j)
    o8[j] = (short)f2bf(par[c0 + j] * h0[j] + par[128 + c0 + j]);
#pragma unroll
  for (int j = 0; j < 4; ++j)
    o8[4 + j] = (short)f2bf(par[c0 + 4 + j] * h1[j] + par[128 + c0 + 4 + j]);
  *reinterpret_cast<short8*>(o + base) = o8;
}

// ---------------- BN apply in-place f32 --------------------------------------
__global__ __launch_bounds__(256) void k_bnapply_f32(float* __restrict__ h,
                                                     const float* __restrict__ par) {
  size_t base = ((size_t)blockIdx.x * 256u + threadIdx.x) * 4;
  if (base >= NND) return;
  int c0 = (int)(base & 127);
  f32x4* hp = reinterpret_cast<f32x4*>(h + base);
  f32x4 v = *hp;
#pragma unroll
  for (int j = 0; j < 4; ++j) v[j] = par[c0 + j] * v[j] + par[128 + c0 + j];
  *hp = v;
}

extern "C" void kernel_launch(void* const* d_in, const int* in_sizes, int n_in,
                              void* d_out, int out_size, void* d_ws, size_t ws_size,
                              hipStream_t stream) {
  const float* x    = (const float*)d_in[0];
  const float* ea   = (const float*)d_in[1];
  const float* w1g  = (const float*)d_in[2];
  const float* b1g  = (const float*)d_in[3];
  const float* w2g  = (const float*)d_in[4];
  const float* b2g  = (const float*)d_in[5];
  const float* bn1g = (const float*)d_in[6];
  const float* bn1b = (const float*)d_in[7];
  const float* ffw1 = (const float*)d_in[8];
  const float* ffb1 = (const float*)d_in[9];
  const float* ffw2 = (const float*)d_in[10];
  const float* ffb2 = (const float*)d_in[11];
  const float* bn2g = (const float*)d_in[12];
  const float* bn2b = (const float*)d_in[13];
  const int*   eidx = (const int*)d_in[14];
  float* out = (float*)d_out;

  char* ws = (char*)d_ws;
  int* elist   = (int*)(ws);                      // 6.4 MB
  int* rs      = (int*)(ws + 6400000);            // (NN+1) ints, doubles as hist
  int* cursor  = (int*)(ws + 6800128);            // NN ints
  int* bsum    = (int*)(ws + 7200128);            // 391 ints
  int* bpre    = (int*)(ws + 7201728);            // 391 ints
  float* stats = (float*)(ws + 7203328);          // 512 f32 (BN1 + BN2)
  float* par   = (float*)(ws + 7205376);          // 512 f32
  unsigned short* w1t  = (unsigned short*)(ws + 7207424);
  unsigned short* w2t  = w1t + 16384;
  unsigned short* fw1t = w2t + 16384;             // 32768 elems
  unsigned short* fw2t = fw1t + 32768;            // 32768 elems
  unsigned short* hbf  = (unsigned short*)(ws + 7404032);   // 25.6 MB (h0, then h1)
  unsigned short* r1bf = (unsigned short*)(ws + 33004032);  // 25.6 MB
  unsigned short* f1bf = (unsigned short*)(ws + 58604032);  // 51.2 MB

  hipMemsetAsync(rs, 0, (NN + 1) * 4, stream);
  hipMemsetAsync(stats, 0, 512 * 4, stream);

  k_cvt_t<<<64, 256, 0, stream>>>(w1g, w1t, 128, 128);
  k_cvt_t<<<64, 256, 0, stream>>>(w2g, w2t, 128, 128);
  k_cvt_t<<<128, 256, 0, stream>>>(ffw1, fw1t, 128, 256);
  k_cvt_t<<<128, 256, 0, stream>>>(ffw2, fw2t, 256, 128);

  // build dst-sorted CSR
  k_hist<<<6250, 256, 0, stream>>>(eidx, rs);
  k_scan1<<<NB_SCAN, 256, 0, stream>>>(rs, bsum);
  k_scan2<<<1, 512, 0, stream>>>(bsum, bpre, rs);
  k_scan3<<<NB_SCAN, 256, 0, stream>>>(rs, bpre, cursor);
  k_scatter<<<6250, 256, 0, stream>>>(eidx, cursor, elist);

  // atomic-free edge aggregation, fused with h0 = x + agg (bf16 out)
  k_gather<<<12500, 256, 0, stream>>>(x, ea, eidx, rs, elist, hbf);

  k_gemm1<<<1563, 256, 0, stream>>>(hbf, w1t, b1g, r1bf);
  k_gemm2<<<1563, 256, 0, stream>>>(r1bf, w2t, b2g, x, out);    // out = hpre1

  k_stats<<<400, 256, 0, stream>>>(out, stats);
  k_bnfin<<<1, 128, 0, stream>>>(stats, bn1g, bn1b, par);
  k_bnapply_bf<<<6250, 256, 0, stream>>>(out, par, hbf);        // hbf = h1 (bf16)

  k_gemm3<<<3125, 256, 0, stream>>>(hbf, fw1t, ffb1, f1bf);
  k_gemm4<<<1563, 256, 0, stream>>>(f1bf, fw2t, ffb2, hbf, out);

  k_stats<<<400, 256, 0, stream>>>(out, stats + 256);
  k_bnfin<<<1, 128, 0, stream>>>(stats + 256, bn2g, bn2b, par + 256);
  k_bnapply_f32<<<12500, 256, 0, stream>>>(out, par + 256);
}

// Round 4
// 755.306 us; speedup vs baseline: 4.0156x; 1.2959x over previous
//
#include <hip/hip_runtime.h>
#include <hip/hip_bf16.h>

#define NN 100000
#define NE 1600000
#define DD 128
#define DFF 256
#define BN_EPS 1e-5f
#define NND ((size_t)NN * DD)
#define NB_SCAN 391  // ceil(NN/256)
#define NTILE 6250   // NN/16

typedef __attribute__((ext_vector_type(8))) short short8;
typedef __attribute__((ext_vector_type(4))) float f32x4;
typedef __attribute__((ext_vector_type(4))) unsigned short us4;

static __device__ __forceinline__ unsigned short f2bf(float f) {
  union { float f; unsigned u; } v; v.f = f;
  unsigned r = v.u + 0x7fffu + ((v.u >> 16) & 1u);
  return (unsigned short)(r >> 16);
}
static __device__ __forceinline__ float bf2f(unsigned short h) {
  union { unsigned u; float f; } v; v.u = ((unsigned)h) << 16;
  return v.f;
}

// ---- misc prep: xbf = bf16(x)  +  4 transposed bf16 weight copies -----------
__global__ __launch_bounds__(256) void k_prep_misc(const float* __restrict__ x,
    unsigned short* __restrict__ xbf,
    const float* __restrict__ w1g, const float* __restrict__ w2g,
    const float* __restrict__ ffw1, const float* __restrict__ ffw2,
    unsigned short* __restrict__ w1t, unsigned short* __restrict__ w2t,
    unsigned short* __restrict__ fw1t, unsigned short* __restrict__ fw2t) {
  int b = blockIdx.x;
  if (b < 6250) {
    size_t base = ((size_t)b * 256u + threadIdx.x) * 8;
    const f32x4* xp = reinterpret_cast<const f32x4*>(x + base);
    f32x4 a0 = xp[0], a1 = xp[1];
    short8 o;
#pragma unroll
    for (int j = 0; j < 4; ++j) o[j] = (short)f2bf(a0[j]);
#pragma unroll
    for (int j = 0; j < 4; ++j) o[4 + j] = (short)f2bf(a1[j]);
    *reinterpret_cast<short8*>(xbf + base) = o;
  } else {
    int i = (b - 6250) * 256 + threadIdx.x;
    if (i < 16384) { int c = i & 127, k = i >> 7; w1t[c * 128 + k] = f2bf(w1g[k * 128 + c]); }
    else if (i < 32768) { i -= 16384; int c = i & 127, k = i >> 7; w2t[c * 128 + k] = f2bf(w2g[k * 128 + c]); }
    else if (i < 65536) { i -= 32768; int c = i & 255, k = i >> 8; fw1t[c * 128 + k] = f2bf(ffw1[k * 256 + c]); }
    else if (i < 98304) { i -= 65536; int c = i & 127, k = i >> 7; fw2t[c * 256 + k] = f2bf(ffw2[k * 128 + c]); }
  }
}

// ---------------- histogram: cnt[dst]++ --------------------------------------
__global__ __launch_bounds__(256) void k_hist(const int* __restrict__ ei,
                                              int* __restrict__ cnt) {
  int e = blockIdx.x * 256 + threadIdx.x;
  if (e >= NE) return;
  atomicAdd(&cnt[ei[NE + e]], 1);
}

// ---------------- scan stage 1 -----------------------------------------------
__global__ __launch_bounds__(256) void k_scan1(const int* __restrict__ cnt,
                                               int* __restrict__ bsum) {
  __shared__ int sh[256];
  int n = blockIdx.x * 256 + threadIdx.x;
  sh[threadIdx.x] = (n < NN) ? cnt[n] : 0;
  __syncthreads();
  for (int off = 128; off > 0; off >>= 1) {
    if (threadIdx.x < off) sh[threadIdx.x] += sh[threadIdx.x + off];
    __syncthreads();
  }
  if (threadIdx.x == 0) bsum[blockIdx.x] = sh[0];
}

// ---------------- scan stage 2 -----------------------------------------------
__global__ __launch_bounds__(512) void k_scan2(const int* __restrict__ bsum,
                                               int* __restrict__ bpre,
                                               int* __restrict__ rs) {
  __shared__ int sh[512];
  int t = threadIdx.x;
  int v = (t < NB_SCAN) ? bsum[t] : 0;
  sh[t] = v;
  __syncthreads();
  for (int off = 1; off < 512; off <<= 1) {
    int u = (t >= off) ? sh[t - off] : 0;
    __syncthreads();
    sh[t] += u;
    __syncthreads();
  }
  if (t < NB_SCAN) bpre[t] = sh[t] - v;
  if (t == NB_SCAN - 1) rs[NN] = sh[t];
}

// ---------------- scan stage 3 + cursor init ---------------------------------
__global__ __launch_bounds__(256) void k_scan3(int* __restrict__ rs,
                                               const int* __restrict__ bpre,
                                               int* __restrict__ cursor) {
  __shared__ int sh[256];
  int n = blockIdx.x * 256 + threadIdx.x;
  int t = threadIdx.x;
  int v = (n < NN) ? rs[n] : 0;
  sh[t] = v;
  __syncthreads();
  for (int off = 1; off < 256; off <<= 1) {
    int u = (t >= off) ? sh[t - off] : 0;
    __syncthreads();
    sh[t] += u;
    __syncthreads();
  }
  if (n < NN) {
    int ex = bpre[blockIdx.x] + sh[t] - v;
    rs[n] = ex;
    cursor[n] = ex;
  }
}

// ---------------- scatter: el2[p] = (edge, src) ------------------------------
__global__ __launch_bounds__(256) void k_scatter(const int* __restrict__ ei,
                                                 int* __restrict__ cursor,
                                                 int2* __restrict__ el2) {
  int e = blockIdx.x * 256 + threadIdx.x;
  if (e >= NE) return;
  int s = ei[e], d = ei[NE + e];
  int p = atomicAdd(&cursor[d], 1);
  el2[p] = make_int2(e, s);
}

// ---- gather: h0bf[n] = bf16(x[n] + sum relu(xbf[src]+ea[e])), pipelined -----
__global__ __launch_bounds__(256) void k_gather(const float* __restrict__ x,
    const unsigned short* __restrict__ xbf, const float* __restrict__ ea,
    const int* __restrict__ rs, const int2* __restrict__ el2,
    unsigned short* __restrict__ h0) {
  int n = blockIdx.x * 8 + (threadIdx.x >> 5);
  int q = threadIdx.x & 31;
  int beg = rs[n], end = rs[n + 1];
  f32x4 acc = (f32x4){0.f, 0.f, 0.f, 0.f};
  int2 A = make_int2(0, 0), B = A;
  if (beg < end) A = el2[beg];
  if (beg + 1 < end) B = el2[beg + 1];
  int i = beg;
  for (; i + 2 <= end; i += 2) {
    f32x4 evA = *(reinterpret_cast<const f32x4*>(ea + (size_t)A.x * DD) + q);
    us4  xvA = *reinterpret_cast<const us4*>(xbf + (size_t)A.y * DD + q * 4);
    f32x4 evB = *(reinterpret_cast<const f32x4*>(ea + (size_t)B.x * DD) + q);
    us4  xvB = *reinterpret_cast<const us4*>(xbf + (size_t)B.y * DD + q * 4);
    int2 C = A, Dn = B;
    if (i + 2 < end) C = el2[i + 2];
    if (i + 3 < end) Dn = el2[i + 3];
#pragma unroll
    for (int c = 0; c < 4; ++c) {
      float mA = bf2f((unsigned short)xvA[c]) + evA[c];
      acc[c] += (mA > 0.f) ? mA : 0.f;
      float mB = bf2f((unsigned short)xvB[c]) + evB[c];
      acc[c] += (mB > 0.f) ? mB : 0.f;
    }
    A = C; B = Dn;
  }
  if (i < end) {  // odd leftover, indices already in A
    f32x4 evA = *(reinterpret_cast<const f32x4*>(ea + (size_t)A.x * DD) + q);
    us4  xvA = *reinterpret_cast<const us4*>(xbf + (size_t)A.y * DD + q * 4);
#pragma unroll
    for (int c = 0; c < 4; ++c) {
      float mA = bf2f((unsigned short)xvA[c]) + evA[c];
      acc[c] += (mA > 0.f) ? mA : 0.f;
    }
  }
  f32x4 xn = *(reinterpret_cast<const f32x4*>(x + (size_t)n * DD) + q);
  union { unsigned short us[4]; unsigned long long u; } pk;
#pragma unroll
  for (int c = 0; c < 4; ++c) pk.us[c] = f2bf(xn[c] + acc[c]);
  *reinterpret_cast<unsigned long long*>(h0 + (size_t)n * DD + q * 4) = pk.u;
}

// ---------------- GEMM1: r1 = relu(h0 @ W1 + b1) -> bf16 ---------------------
__global__ __launch_bounds__(256) void k_gemm1(const unsigned short* __restrict__ A,
    const unsigned short* __restrict__ WT, const float* __restrict__ bias,
    unsigned short* __restrict__ O) {
  int lane = threadIdx.x & 63, w = threadIdx.x >> 6;
  int tile = blockIdx.x * 4 + w;
  if (tile >= NTILE) return;
  int l15 = lane & 15, g = lane >> 4;
  int row0 = tile * 16;
  f32x4 acc[8];
#pragma unroll
  for (int ct = 0; ct < 8; ++ct) {
    float b = bias[ct * 16 + l15];
    acc[ct] = (f32x4){b, b, b, b};
  }
  short8 a[4];
#pragma unroll
  for (int kt = 0; kt < 4; ++kt)
    a[kt] = *reinterpret_cast<const short8*>(A + (size_t)(row0 + l15) * DD + kt * 32 + g * 8);
#pragma unroll
  for (int kt = 0; kt < 4; ++kt) {
    int k0 = kt * 32 + g * 8;
#pragma unroll
    for (int ct = 0; ct < 8; ++ct) {
      int c = ct * 16 + l15;
      short8 b = *reinterpret_cast<const short8*>(WT + (size_t)c * DD + k0);
      acc[ct] = __builtin_amdgcn_mfma_f32_16x16x32_bf16(a[kt], b, acc[ct], 0, 0, 0);
    }
  }
#pragma unroll
  for (int ct = 0; ct < 8; ++ct) {
    int c = ct * 16 + l15;
#pragma unroll
    for (int r = 0; r < 4; ++r) {
      int row = row0 + g * 4 + r;
      float v = acc[ct][r];
      v = v > 0.f ? v : 0.f;
      O[(size_t)row * DD + c] = f2bf(v);
    }
  }
}

// ------- GEMM2: out = x + relu(r1 @ W2 + b2) -> f32, + BN1 stats -------------
__global__ __launch_bounds__(256) void k_gemm2(const unsigned short* __restrict__ A,
    const unsigned short* __restrict__ WT, const float* __restrict__ bias,
    const float* __restrict__ x, float* __restrict__ O, float* __restrict__ stats) {
  __shared__ float lds_s[128], lds_q[128];
  if (threadIdx.x < 128) { lds_s[threadIdx.x] = 0.f; lds_q[threadIdx.x] = 0.f; }
  __syncthreads();
  int lane = threadIdx.x & 63, w = threadIdx.x >> 6;
  int tile = blockIdx.x * 4 + w;
  int l15 = lane & 15, g = lane >> 4;
  if (tile < NTILE) {
    int row0 = tile * 16;
    f32x4 acc[8];
#pragma unroll
    for (int ct = 0; ct < 8; ++ct) {
      float b = bias[ct * 16 + l15];
      acc[ct] = (f32x4){b, b, b, b};
    }
    short8 a[4];
#pragma unroll
    for (int kt = 0; kt < 4; ++kt)
      a[kt] = *reinterpret_cast<const short8*>(A + (size_t)(row0 + l15) * DD + kt * 32 + g * 8);
#pragma unroll
    for (int kt = 0; kt < 4; ++kt) {
      int k0 = kt * 32 + g * 8;
#pragma unroll
      for (int ct = 0; ct < 8; ++ct) {
        int c = ct * 16 + l15;
        short8 b = *reinterpret_cast<const short8*>(WT + (size_t)c * DD + k0);
        acc[ct] = __builtin_amdgcn_mfma_f32_16x16x32_bf16(a[kt], b, acc[ct], 0, 0, 0);
      }
    }
#pragma unroll
    for (int ct = 0; ct < 8; ++ct) {
      int c = ct * 16 + l15;
      float s = 0.f, q = 0.f;
#pragma unroll
      for (int r = 0; r < 4; ++r) {
        int row = row0 + g * 4 + r;
        float v = acc[ct][r];
        v = v > 0.f ? v : 0.f;
        v += x[(size_t)row * DD + c];
        O[(size_t)row * DD + c] = v;
        s += v; q += v * v;
      }
      s += __shfl_xor(s, 16); s += __shfl_xor(s, 32);
      q += __shfl_xor(q, 16); q += __shfl_xor(q, 32);
      if (g == 0) { atomicAdd(&lds_s[c], s); atomicAdd(&lds_q[c], q); }
    }
  }
  __syncthreads();
  if (threadIdx.x < 128) {
    atomicAdd(&stats[threadIdx.x], lds_s[threadIdx.x]);
    atomicAdd(&stats[128 + threadIdx.x], lds_q[threadIdx.x]);
  }
}

// ---------------- BN1 finalize -> par ----------------------------------------
__global__ void k_bnfin(const float* __restrict__ st, const float* __restrict__ gm,
                        const float* __restrict__ bt, float* __restrict__ par) {
  int c = threadIdx.x;
  float mean = st[c] * (1.f / NN);
  float var = st[128 + c] * (1.f / NN) - mean * mean;
  float sc = gm[c] * rsqrtf(var + BN_EPS);
  par[c] = sc;
  par[128 + c] = bt[c] - mean * sc;
}

// ------- GEMM3: f1 = relu(bn1(out) @ FFW1 + fb1) -> bf16 (BN applied on A) ---
__global__ __launch_bounds__(256) void k_gemm3(const float* __restrict__ H,
    const float* __restrict__ par, const unsigned short* __restrict__ WT,
    const float* __restrict__ bias, unsigned short* __restrict__ O) {
  int lane = threadIdx.x & 63, w = threadIdx.x >> 6;
  int colhalf = w & 1;
  int tile = blockIdx.x * 2 + (w >> 1);
  if (tile >= NTILE) return;
  int l15 = lane & 15, g = lane >> 4;
  int row0 = tile * 16;
  f32x4 acc[8];
#pragma unroll
  for (int ct = 0; ct < 8; ++ct) {
    float b = bias[colhalf * 128 + ct * 16 + l15];
    acc[ct] = (f32x4){b, b, b, b};
  }
  const float* arow = H + (size_t)(row0 + l15) * DD;
  short8 a[4];
#pragma unroll
  for (int kt = 0; kt < 4; ++kt) {
    int k0 = kt * 32 + g * 8;
    f32x4 u0 = *reinterpret_cast<const f32x4*>(arow + k0);
    f32x4 u1 = *reinterpret_cast<const f32x4*>(arow + k0 + 4);
    f32x4 sc0 = *reinterpret_cast<const f32x4*>(par + k0);
    f32x4 sc1 = *reinterpret_cast<const f32x4*>(par + k0 + 4);
    f32x4 sh0 = *reinterpret_cast<const f32x4*>(par + 128 + k0);
    f32x4 sh1 = *reinterpret_cast<const f32x4*>(par + 128 + k0 + 4);
    short8 af;
#pragma unroll
    for (int j = 0; j < 4; ++j) af[j] = (short)f2bf(sc0[j] * u0[j] + sh0[j]);
#pragma unroll
    for (int j = 0; j < 4; ++j) af[4 + j] = (short)f2bf(sc1[j] * u1[j] + sh1[j]);
    a[kt] = af;
  }
#pragma unroll
  for (int kt = 0; kt < 4; ++kt) {
    int k0 = kt * 32 + g * 8;
#pragma unroll
    for (int ct = 0; ct < 8; ++ct) {
      int c = colhalf * 128 + ct * 16 + l15;
      short8 b = *reinterpret_cast<const short8*>(WT + (size_t)c * DD + k0);
      acc[ct] = __builtin_amdgcn_mfma_f32_16x16x32_bf16(a[kt], b, acc[ct], 0, 0, 0);
    }
  }
#pragma unroll
  for (int ct = 0; ct < 8; ++ct) {
    int c = colhalf * 128 + ct * 16 + l15;
#pragma unroll
    for (int r = 0; r < 4; ++r) {
      int row = row0 + g * 4 + r;
      float v = acc[ct][r];
      v = v > 0.f ? v : 0.f;
      O[(size_t)row * DFF + c] = f2bf(v);
    }
  }
}

// ------- GEMM4: out = bn1(out) + f1 @ FFW2 + fb2 -> f32, + BN2 stats ---------
__global__ __launch_bounds__(256) void k_gemm4(const unsigned short* __restrict__ A,
    const unsigned short* __restrict__ WT, const float* __restrict__ bias,
    const float* __restrict__ par, float* __restrict__ O, float* __restrict__ stats) {
  __shared__ float lds_s[128], lds_q[128];
  if (threadIdx.x < 128) { lds_s[threadIdx.x] = 0.f; lds_q[threadIdx.x] = 0.f; }
  __syncthreads();
  int lane = threadIdx.x & 63, w = threadIdx.x >> 6;
  int tile = blockIdx.x * 4 + w;
  int l15 = lane & 15, g = lane >> 4;
  if (tile < NTILE) {
    int row0 = tile * 16;
    f32x4 acc[8];
#pragma unroll
    for (int ct = 0; ct < 8; ++ct) {
      float b = bias[ct * 16 + l15];
      acc[ct] = (f32x4){b, b, b, b};
    }
    short8 a[8];
#pragma unroll
    for (int kt = 0; kt < 8; ++kt)
      a[kt] = *reinterpret_cast<const short8*>(A + (size_t)(row0 + l15) * DFF + kt * 32 + g * 8);
#pragma unroll 2
    for (int kt = 0; kt < 8; ++kt) {
      int k0 = kt * 32 + g * 8;
#pragma unroll
      for (int ct = 0; ct < 8; ++ct) {
        int c = ct * 16 + l15;
        short8 b = *reinterpret_cast<const short8*>(WT + (size_t)c * DFF + k0);
        acc[ct] = __builtin_amdgcn_mfma_f32_16x16x32_bf16(a[kt], b, acc[ct], 0, 0, 0);
      }
    }
#pragma unroll
    for (int ct = 0; ct < 8; ++ct) {
      int c = ct * 16 + l15;
      float sc = par[c], sh = par[128 + c];
      float s = 0.f, q = 0.f;
#pragma unroll
      for (int r = 0; r < 4; ++r) {
        int row = row0 + g * 4 + r;
        float h1v = sc * O[(size_t)row * DD + c] + sh;   // recompute bn1(out)
        float v = acc[ct][r] + h1v;
        O[(size_t)row * DD + c] = v;
        s += v; q += v * v;
      }
      s += __shfl_xor(s, 16); s += __shfl_xor(s, 32);
      q += __shfl_xor(q, 16); q += __shfl_xor(q, 32);
      if (g == 0) { atomicAdd(&lds_s[c], s); atomicAdd(&lds_q[c], q); }
    }
  }
  __syncthreads();
  if (threadIdx.x < 128) {
    atomicAdd(&stats[threadIdx.x], lds_s[threadIdx.x]);
    atomicAdd(&stats[128 + threadIdx.x], lds_q[threadIdx.x]);
  }
}

// ------- final: out = bn2(out) in place (BN2 finalize fused) -----------------
__global__ __launch_bounds__(256) void k_bnfinal(float* __restrict__ h,
    const float* __restrict__ st, const float* __restrict__ gm,
    const float* __restrict__ bt) {
  size_t base = ((size_t)blockIdx.x * 256u + threadIdx.x) * 4;
  int c0 = (int)(base & 127);
  f32x4 v = *reinterpret_cast<f32x4*>(h + base);
#pragma unroll
  for (int j = 0; j < 4; ++j) {
    int c = c0 + j;
    float mean = st[c] * (1.f / NN);
    float var = st[128 + c] * (1.f / NN) - mean * mean;
    float sc = gm[c] * rsqrtf(var + BN_EPS);
    float sh = bt[c] - mean * sc;
    v[j] = sc * v[j] + sh;
  }
  *reinterpret_cast<f32x4*>(h + base) = v;
}

extern "C" void kernel_launch(void* const* d_in, const int* in_sizes, int n_in,
                              void* d_out, int out_size, void* d_ws, size_t ws_size,
                              hipStream_t stream) {
  const float* x    = (const float*)d_in[0];
  const float* ea   = (const float*)d_in[1];
  const float* w1g  = (const float*)d_in[2];
  const float* b1g  = (const float*)d_in[3];
  const float* w2g  = (const float*)d_in[4];
  const float* b2g  = (const float*)d_in[5];
  const float* bn1g = (const float*)d_in[6];
  const float* bn1b = (const float*)d_in[7];
  const float* ffw1 = (const float*)d_in[8];
  const float* ffb1 = (const float*)d_in[9];
  const float* ffw2 = (const float*)d_in[10];
  const float* ffb2 = (const float*)d_in[11];
  const float* bn2g = (const float*)d_in[12];
  const float* bn2b = (const float*)d_in[13];
  const int*   eidx = (const int*)d_in[14];
  float* out = (float*)d_out;

  char* ws = (char*)d_ws;
  int2* el2    = (int2*)(ws);                         // 12.8 MB
  int*  rs     = (int*)(ws + 12800000);               // (NN+1) ints
  int*  cursor = (int*)(ws + 13200128);               // NN ints
  int*  bsum   = (int*)(ws + 13600128);               // 391 ints
  int*  bpre   = (int*)(ws + 13601728);               // 391 ints
  float* stats = (float*)(ws + 13603328);             // 512 f32 (BN1 + BN2)
  float* par   = (float*)(ws + 13605376);             // 256 f32 (BN1 scale/shift)
  unsigned short* w1t  = (unsigned short*)(ws + 13607424);
  unsigned short* w2t  = w1t + 16384;
  unsigned short* fw1t = w2t + 16384;                 // 32768 elems
  unsigned short* fw2t = fw1t + 32768;                // 32768 elems
  unsigned short* xbf  = (unsigned short*)(ws + 13804032);  // 25.6 MB
  unsigned short* hbf  = (unsigned short*)(ws + 39404032);  // 25.6 MB (h0)
  unsigned short* r1bf = (unsigned short*)(ws + 65004032);  // 25.6 MB
  unsigned short* f1bf = (unsigned short*)(ws + 90604032);  // 51.2 MB

  hipMemsetAsync(rs, 0, (NN + 1) * 4, stream);
  hipMemsetAsync(stats, 0, 512 * 4, stream);

  k_prep_misc<<<6634, 256, 0, stream>>>(x, xbf, w1g, w2g, ffw1, ffw2,
                                        w1t, w2t, fw1t, fw2t);

  // build dst-sorted CSR with (edge,src) pairs
  k_hist<<<6250, 256, 0, stream>>>(eidx, rs);
  k_scan1<<<NB_SCAN, 256, 0, stream>>>(rs, bsum);
  k_scan2<<<1, 512, 0, stream>>>(bsum, bpre, rs);
  k_scan3<<<NB_SCAN, 256, 0, stream>>>(rs, bpre, cursor);
  k_scatter<<<6250, 256, 0, stream>>>(eidx, cursor, el2);

  // atomic-free edge aggregation, fused with h0 = x + agg (bf16 out)
  k_gather<<<12500, 256, 0, stream>>>(x, xbf, ea, rs, el2, hbf);

  k_gemm1<<<1563, 256, 0, stream>>>(hbf, w1t, b1g, r1bf);
  k_gemm2<<<1563, 256, 0, stream>>>(r1bf, w2t, b2g, x, out, stats);   // out = hpre1, +stats1
  k_bnfin<<<1, 128, 0, stream>>>(stats, bn1g, bn1b, par);
  k_gemm3<<<3125, 256, 0, stream>>>(out, par, fw1t, ffb1, f1bf);      // bn1 applied on A
  k_gemm4<<<1563, 256, 0, stream>>>(f1bf, fw2t, ffb2, par, out, stats + 256); // +stats2
  k_bnfinal<<<12500, 256, 0, stream>>>(out, stats + 256, bn2g, bn2b);  // FIX: BN2 stats
}

// Round 5
// 721.992 us; speedup vs baseline: 4.2009x; 1.0461x over previous
//
#include <hip/hip_runtime.h>
#include <hip/hip_bf16.h>

#define NN 100000
#define NE 1600000
#define DD 128
#define DFF 256
#define BN_EPS 1e-5f
#define NND ((size_t)NN * DD)
#define NB_SCAN 391  // ceil(NN/256)
#define NTILE 6250   // NN/16

typedef __attribute__((ext_vector_type(8))) short short8;
typedef __attribute__((ext_vector_type(4))) float f32x4;
typedef __attribute__((ext_vector_type(4))) unsigned short us4;

static __device__ __forceinline__ unsigned short f2bf(float f) {
  union { float f; unsigned u; } v; v.f = f;
  unsigned r = v.u + 0x7fffu + ((v.u >> 16) & 1u);
  return (unsigned short)(r >> 16);
}
static __device__ __forceinline__ float bf2f(unsigned short h) {
  union { unsigned u; float f; } v; v.u = ((unsigned)h) << 16;
  return v.f;
}

// ---- misc prep: xbf = bf16(x)  +  4 transposed bf16 weight copies -----------
__global__ __launch_bounds__(256) void k_prep_misc(const float* __restrict__ x,
    unsigned short* __restrict__ xbf,
    const float* __restrict__ w1g, const float* __restrict__ w2g,
    const float* __restrict__ ffw1, const float* __restrict__ ffw2,
    unsigned short* __restrict__ w1t, unsigned short* __restrict__ w2t,
    unsigned short* __restrict__ fw1t, unsigned short* __restrict__ fw2t) {
  int b = blockIdx.x;
  if (b < 6250) {
    size_t base = ((size_t)b * 256u + threadIdx.x) * 8;
    const f32x4* xp = reinterpret_cast<const f32x4*>(x + base);
    f32x4 a0 = xp[0], a1 = xp[1];
    short8 o;
#pragma unroll
    for (int j = 0; j < 4; ++j) o[j] = (short)f2bf(a0[j]);
#pragma unroll
    for (int j = 0; j < 4; ++j) o[4 + j] = (short)f2bf(a1[j]);
    *reinterpret_cast<short8*>(xbf + base) = o;
  } else {
    int i = (b - 6250) * 256 + threadIdx.x;
    if (i < 16384) { int c = i & 127, k = i >> 7; w1t[c * 128 + k] = f2bf(w1g[k * 128 + c]); }
    else if (i < 32768) { i -= 16384; int c = i & 127, k = i >> 7; w2t[c * 128 + k] = f2bf(w2g[k * 128 + c]); }
    else if (i < 65536) { i -= 32768; int c = i & 255, k = i >> 8; fw1t[c * 128 + k] = f2bf(ffw1[k * 256 + c]); }
    else if (i < 98304) { i -= 65536; int c = i & 127, k = i >> 7; fw2t[c * 256 + k] = f2bf(ffw2[k * 128 + c]); }
  }
}

// ---------------- histogram: cnt[dst]++ --------------------------------------
__global__ __launch_bounds__(256) void k_hist(const int* __restrict__ ei,
                                              int* __restrict__ cnt) {
  int e = blockIdx.x * 256 + threadIdx.x;
  if (e >= NE) return;
  atomicAdd(&cnt[ei[NE + e]], 1);
}

// ---------------- scan stage 1 -----------------------------------------------
__global__ __launch_bounds__(256) void k_scan1(const int* __restrict__ cnt,
                                               int* __restrict__ bsum) {
  __shared__ int sh[256];
  int n = blockIdx.x * 256 + threadIdx.x;
  sh[threadIdx.x] = (n < NN) ? cnt[n] : 0;
  __syncthreads();
  for (int off = 128; off > 0; off >>= 1) {
    if (threadIdx.x < off) sh[threadIdx.x] += sh[threadIdx.x + off];
    __syncthreads();
  }
  if (threadIdx.x == 0) bsum[blockIdx.x] = sh[0];
}

// ---------------- scan stage 2 -----------------------------------------------
__global__ __launch_bounds__(512) void k_scan2(const int* __restrict__ bsum,
                                               int* __restrict__ bpre,
                                               int* __restrict__ rs) {
  __shared__ int sh[512];
  int t = threadIdx.x;
  int v = (t < NB_SCAN) ? bsum[t] : 0;
  sh[t] = v;
  __syncthreads();
  for (int off = 1; off < 512; off <<= 1) {
    int u = (t >= off) ? sh[t - off] : 0;
    __syncthreads();
    sh[t] += u;
    __syncthreads();
  }
  if (t < NB_SCAN) bpre[t] = sh[t] - v;
  if (t == NB_SCAN - 1) rs[NN] = sh[t];
}

// ---------------- scan stage 3 + cursor init ---------------------------------
__global__ __launch_bounds__(256) void k_scan3(int* __restrict__ rs,
                                               const int* __restrict__ bpre,
                                               int* __restrict__ cursor) {
  __shared__ int sh[256];
  int n = blockIdx.x * 256 + threadIdx.x;
  int t = threadIdx.x;
  int v = (n < NN) ? rs[n] : 0;
  sh[t] = v;
  __syncthreads();
  for (int off = 1; off < 256; off <<= 1) {
    int u = (t >= off) ? sh[t - off] : 0;
    __syncthreads();
    sh[t] += u;
    __syncthreads();
  }
  if (n < NN) {
    int ex = bpre[blockIdx.x] + sh[t] - v;
    rs[n] = ex;
    cursor[n] = ex;
  }
}

// ---------------- scatter: el2[p] = (edge, src) ------------------------------
__global__ __launch_bounds__(256) void k_scatter(const int* __restrict__ ei,
                                                 int* __restrict__ cursor,
                                                 int2* __restrict__ el2) {
  int e = blockIdx.x * 256 + threadIdx.x;
  if (e >= NE) return;
  int s = ei[e], d = ei[NE + e];
  int p = atomicAdd(&cursor[d], 1);
  el2[p] = make_int2(e, s);
}

// ---- gather: h0bf[n] = bf16(xbf[n] + sum relu(xbf[src]+ea[e])), 4-deep ------
__global__ __launch_bounds__(256) void k_gather(
    const unsigned short* __restrict__ xbf, const float* __restrict__ ea,
    const int* __restrict__ rs, const int2* __restrict__ el2,
    unsigned short* __restrict__ h0) {
  int n = blockIdx.x * 8 + (threadIdx.x >> 5);
  int q = threadIdx.x & 31;
  int beg = rs[n], end = rs[n + 1];
  f32x4 acc = (f32x4){0.f, 0.f, 0.f, 0.f};
  int2 E0 = make_int2(0, 0), E1 = E0, E2 = E0, E3 = E0;
  int i = beg;
  if (i     < end) E0 = el2[i];
  if (i + 1 < end) E1 = el2[i + 1];
  if (i + 2 < end) E2 = el2[i + 2];
  if (i + 3 < end) E3 = el2[i + 3];
  for (; i + 4 <= end; i += 4) {
    f32x4 ev0 = *(reinterpret_cast<const f32x4*>(ea + (size_t)E0.x * DD) + q);
    us4  xv0 = *reinterpret_cast<const us4*>(xbf + (size_t)E0.y * DD + q * 4);
    f32x4 ev1 = *(reinterpret_cast<const f32x4*>(ea + (size_t)E1.x * DD) + q);
    us4  xv1 = *reinterpret_cast<const us4*>(xbf + (size_t)E1.y * DD + q * 4);
    f32x4 ev2 = *(reinterpret_cast<const f32x4*>(ea + (size_t)E2.x * DD) + q);
    us4  xv2 = *reinterpret_cast<const us4*>(xbf + (size_t)E2.y * DD + q * 4);
    f32x4 ev3 = *(reinterpret_cast<const f32x4*>(ea + (size_t)E3.x * DD) + q);
    us4  xv3 = *reinterpret_cast<const us4*>(xbf + (size_t)E3.y * DD + q * 4);
    int2 N0 = E0, N1 = E1, N2 = E2, N3 = E3;
    if (i + 4 < end) N0 = el2[i + 4];
    if (i + 5 < end) N1 = el2[i + 5];
    if (i + 6 < end) N2 = el2[i + 6];
    if (i + 7 < end) N3 = el2[i + 7];
#pragma unroll
    for (int c = 0; c < 4; ++c) {
      float m0 = bf2f((unsigned short)xv0[c]) + ev0[c];
      acc[c] += (m0 > 0.f) ? m0 : 0.f;
      float m1 = bf2f((unsigned short)xv1[c]) + ev1[c];
      acc[c] += (m1 > 0.f) ? m1 : 0.f;
      float m2 = bf2f((unsigned short)xv2[c]) + ev2[c];
      acc[c] += (m2 > 0.f) ? m2 : 0.f;
      float m3 = bf2f((unsigned short)xv3[c]) + ev3[c];
      acc[c] += (m3 > 0.f) ? m3 : 0.f;
    }
    E0 = N0; E1 = N1; E2 = N2; E3 = N3;
  }
  // tail (0..3 edges), indices already staged in E0..E2
  if (i < end) {
    f32x4 ev = *(reinterpret_cast<const f32x4*>(ea + (size_t)E0.x * DD) + q);
    us4  xv = *reinterpret_cast<const us4*>(xbf + (size_t)E0.y * DD + q * 4);
#pragma unroll
    for (int c = 0; c < 4; ++c) {
      float m = bf2f((unsigned short)xv[c]) + ev[c];
      acc[c] += (m > 0.f) ? m : 0.f;
    }
  }
  if (i + 1 < end) {
    f32x4 ev = *(reinterpret_cast<const f32x4*>(ea + (size_t)E1.x * DD) + q);
    us4  xv = *reinterpret_cast<const us4*>(xbf + (size_t)E1.y * DD + q * 4);
#pragma unroll
    for (int c = 0; c < 4; ++c) {
      float m = bf2f((unsigned short)xv[c]) + ev[c];
      acc[c] += (m > 0.f) ? m : 0.f;
    }
  }
  if (i + 2 < end) {
    f32x4 ev = *(reinterpret_cast<const f32x4*>(ea + (size_t)E2.x * DD) + q);
    us4  xv = *reinterpret_cast<const us4*>(xbf + (size_t)E2.y * DD + q * 4);
#pragma unroll
    for (int c = 0; c < 4; ++c) {
      float m = bf2f((unsigned short)xv[c]) + ev[c];
      acc[c] += (m > 0.f) ? m : 0.f;
    }
  }
  us4 xs = *reinterpret_cast<const us4*>(xbf + (size_t)n * DD + q * 4);
  union { unsigned short us[4]; unsigned long long u; } pk;
#pragma unroll
  for (int c = 0; c < 4; ++c) pk.us[c] = f2bf(bf2f((unsigned short)xs[c]) + acc[c]);
  *reinterpret_cast<unsigned long long*>(h0 + (size_t)n * DD + q * 4) = pk.u;
}

// ------- MLP1 fused: out = x + relu(relu(h0@W1+b1)@W2+b2), + BN1 stats -------
#define TR1 136  // padded LDS row stride (elems): 272B = 17*16, 16B-aligned
__global__ __launch_bounds__(256) void k_mlp1(const unsigned short* __restrict__ A,
    const unsigned short* __restrict__ W1T, const float* __restrict__ b1,
    const unsigned short* __restrict__ W2T, const float* __restrict__ b2,
    const float* __restrict__ x, float* __restrict__ O, float* __restrict__ stats) {
  __shared__ unsigned short tr[4][16 * TR1];
  __shared__ float lds_s[128], lds_q[128];
  if (threadIdx.x < 128) { lds_s[threadIdx.x] = 0.f; lds_q[threadIdx.x] = 0.f; }
  int lane = threadIdx.x & 63, w = threadIdx.x >> 6;
  int tile = blockIdx.x * 4 + w;
  int l15 = lane & 15, g = lane >> 4;
  int row0 = tile * 16;
  __syncthreads();
  if (tile < NTILE) {
    f32x4 acc[8];
#pragma unroll
    for (int ct = 0; ct < 8; ++ct) {
      float b = b1[ct * 16 + l15];
      acc[ct] = (f32x4){b, b, b, b};
    }
    short8 a[4];
#pragma unroll
    for (int kt = 0; kt < 4; ++kt)
      a[kt] = *reinterpret_cast<const short8*>(A + (size_t)(row0 + l15) * DD + kt * 32 + g * 8);
#pragma unroll
    for (int kt = 0; kt < 4; ++kt) {
      int k0 = kt * 32 + g * 8;
#pragma unroll
      for (int ct = 0; ct < 8; ++ct) {
        int c = ct * 16 + l15;
        short8 b = *reinterpret_cast<const short8*>(W1T + (size_t)c * DD + k0);
        acc[ct] = __builtin_amdgcn_mfma_f32_16x16x32_bf16(a[kt], b, acc[ct], 0, 0, 0);
      }
    }
    // relu -> bf16 -> LDS transpose
#pragma unroll
    for (int ct = 0; ct < 8; ++ct) {
#pragma unroll
      for (int r = 0; r < 4; ++r) {
        float v = acc[ct][r];
        v = v > 0.f ? v : 0.f;
        tr[w][(g * 4 + r) * TR1 + ct * 16 + l15] = f2bf(v);
      }
    }
  }
  __syncthreads();
  if (tile < NTILE) {
    short8 a2[4];
#pragma unroll
    for (int kt = 0; kt < 4; ++kt)
      a2[kt] = *reinterpret_cast<const short8*>(&tr[w][l15 * TR1 + kt * 32 + g * 8]);
    f32x4 acc2[8];
#pragma unroll
    for (int ct = 0; ct < 8; ++ct) {
      float b = b2[ct * 16 + l15];
      acc2[ct] = (f32x4){b, b, b, b};
    }
#pragma unroll
    for (int kt = 0; kt < 4; ++kt) {
      int k0 = kt * 32 + g * 8;
#pragma unroll
      for (int ct = 0; ct < 8; ++ct) {
        int c = ct * 16 + l15;
        short8 b = *reinterpret_cast<const short8*>(W2T + (size_t)c * DD + k0);
        acc2[ct] = __builtin_amdgcn_mfma_f32_16x16x32_bf16(a2[kt], b, acc2[ct], 0, 0, 0);
      }
    }
#pragma unroll
    for (int ct = 0; ct < 8; ++ct) {
      int c = ct * 16 + l15;
      float s = 0.f, q = 0.f;
#pragma unroll
      for (int r = 0; r < 4; ++r) {
        int row = row0 + g * 4 + r;
        float v = acc2[ct][r];
        v = v > 0.f ? v : 0.f;
        v += x[(size_t)row * DD + c];
        O[(size_t)row * DD + c] = v;
        s += v; q += v * v;
      }
      s += __shfl_xor(s, 16); s += __shfl_xor(s, 32);
      q += __shfl_xor(q, 16); q += __shfl_xor(q, 32);
      if (g == 0) { atomicAdd(&lds_s[c], s); atomicAdd(&lds_q[c], q); }
    }
  }
  __syncthreads();
  if (threadIdx.x < 128) {
    atomicAdd(&stats[threadIdx.x], lds_s[threadIdx.x]);
    atomicAdd(&stats[128 + threadIdx.x], lds_q[threadIdx.x]);
  }
}

// ---------------- BN1 finalize -> par ----------------------------------------
__global__ void k_bnfin(const float* __restrict__ st, const float* __restrict__ gm,
                        const float* __restrict__ bt, float* __restrict__ par) {
  int c = threadIdx.x;
  float mean = st[c] * (1.f / NN);
  float var = st[128 + c] * (1.f / NN) - mean * mean;
  float sc = gm[c] * rsqrtf(var + BN_EPS);
  par[c] = sc;
  par[128 + c] = bt[c] - mean * sc;
}

// ------- MLP2 fused: out = bn1(out) + relu(bn1(out)@FFW1+fb1)@FFW2+fb2 -------
//         (+ BN2 stats)
#define TR2 264  // padded LDS row stride (elems): 528B = 33*16, 16B-aligned
__global__ __launch_bounds__(256) void k_mlp2(const float* __restrict__ H,
    const float* __restrict__ par, const unsigned short* __restrict__ FW1T,
    const float* __restrict__ fb1, const unsigned short* __restrict__ FW2T,
    const float* __restrict__ fb2, float* __restrict__ O, float* __restrict__ stats) {
  __shared__ unsigned short tr[4][16 * TR2];
  __shared__ float lds_s[128], lds_q[128];
  if (threadIdx.x < 128) { lds_s[threadIdx.x] = 0.f; lds_q[threadIdx.x] = 0.f; }
  int lane = threadIdx.x & 63, w = threadIdx.x >> 6;
  int tile = blockIdx.x * 4 + w;
  int l15 = lane & 15, g = lane >> 4;
  int row0 = tile * 16;
  __syncthreads();
  if (tile < NTILE) {
    // stage 1: A = bn1(H) on the fly; f1 = relu(A @ FFW1 + fb1)  (16x256)
    const float* arow = H + (size_t)(row0 + l15) * DD;
    short8 a1[4];
#pragma unroll
    for (int kt = 0; kt < 4; ++kt) {
      int k0 = kt * 32 + g * 8;
      f32x4 u0 = *reinterpret_cast<const f32x4*>(arow + k0);
      f32x4 u1 = *reinterpret_cast<const f32x4*>(arow + k0 + 4);
      f32x4 sc0 = *reinterpret_cast<const f32x4*>(par + k0);
      f32x4 sc1 = *reinterpret_cast<const f32x4*>(par + k0 + 4);
      f32x4 sh0 = *reinterpret_cast<const f32x4*>(par + 128 + k0);
      f32x4 sh1 = *reinterpret_cast<const f32x4*>(par + 128 + k0 + 4);
      short8 af;
#pragma unroll
      for (int j = 0; j < 4; ++j) af[j] = (short)f2bf(sc0[j] * u0[j] + sh0[j]);
#pragma unroll
      for (int j = 0; j < 4; ++j) af[4 + j] = (short)f2bf(sc1[j] * u1[j] + sh1[j]);
      a1[kt] = af;
    }
    f32x4 acc1[16];
#pragma unroll
    for (int ct = 0; ct < 16; ++ct) {
      float b = fb1[ct * 16 + l15];
      acc1[ct] = (f32x4){b, b, b, b};
    }
#pragma unroll
    for (int kt = 0; kt < 4; ++kt) {
      int k0 = kt * 32 + g * 8;
#pragma unroll
      for (int ct = 0; ct < 16; ++ct) {
        int c = ct * 16 + l15;
        short8 b = *reinterpret_cast<const short8*>(FW1T + (size_t)c * DD + k0);
        acc1[ct] = __builtin_amdgcn_mfma_f32_16x16x32_bf16(a1[kt], b, acc1[ct], 0, 0, 0);
      }
    }
#pragma unroll
    for (int ct = 0; ct < 16; ++ct) {
#pragma unroll
      for (int r = 0; r < 4; ++r) {
        float v = acc1[ct][r];
        v = v > 0.f ? v : 0.f;
        tr[w][(g * 4 + r) * TR2 + ct * 16 + l15] = f2bf(v);
      }
    }
  }
  __syncthreads();
  if (tile < NTILE) {
    // stage 2: out = bn1(H) + f1 @ FFW2 + fb2   (K=256)
    short8 a2[8];
#pragma unroll
    for (int kt = 0; kt < 8; ++kt)
      a2[kt] = *reinterpret_cast<const short8*>(&tr[w][l15 * TR2 + kt * 32 + g * 8]);
    f32x4 acc2[8];
#pragma unroll
    for (int ct = 0; ct < 8; ++ct) {
      float b = fb2[ct * 16 + l15];
      acc2[ct] = (f32x4){b, b, b, b};
    }
#pragma unroll 2
    for (int kt = 0; kt < 8; ++kt) {
      int k0 = kt * 32 + g * 8;
#pragma unroll
      for (int ct = 0; ct < 8; ++ct) {
        int c = ct * 16 + l15;
        short8 b = *reinterpret_cast<const short8*>(FW2T + (size_t)c * DFF + k0);
        acc2[ct] = __builtin_amdgcn_mfma_f32_16x16x32_bf16(a2[kt], b, acc2[ct], 0, 0, 0);
      }
    }
#pragma unroll
    for (int ct = 0; ct < 8; ++ct) {
      int c = ct * 16 + l15;
      float sc = par[c], sh = par[128 + c];
      float s = 0.f, q = 0.f;
#pragma unroll
      for (int r = 0; r < 4; ++r) {
        int row = row0 + g * 4 + r;
        float h1v = sc * O[(size_t)row * DD + c] + sh;  // bn1(out) residual
        float v = acc2[ct][r] + h1v;
        O[(size_t)row * DD + c] = v;
        s += v; q += v * v;
      }
      s += __shfl_xor(s, 16); s += __shfl_xor(s, 32);
      q += __shfl_xor(q, 16); q += __shfl_xor(q, 32);
      if (g == 0) { atomicAdd(&lds_s[c], s); atomicAdd(&lds_q[c], q); }
    }
  }
  __syncthreads();
  if (threadIdx.x < 128) {
    atomicAdd(&stats[threadIdx.x], lds_s[threadIdx.x]);
    atomicAdd(&stats[128 + threadIdx.x], lds_q[threadIdx.x]);
  }
}

// ------- final: out = bn2(out) in place (BN2 finalize fused) -----------------
__global__ __launch_bounds__(256) void k_bnfinal(float* __restrict__ h,
    const float* __restrict__ st, const float* __restrict__ gm,
    const float* __restrict__ bt) {
  size_t base = ((size_t)blockIdx.x * 256u + threadIdx.x) * 4;
  int c0 = (int)(base & 127);
  f32x4 v = *reinterpret_cast<f32x4*>(h + base);
#pragma unroll
  for (int j = 0; j < 4; ++j) {
    int c = c0 + j;
    float mean = st[c] * (1.f / NN);
    float var = st[128 + c] * (1.f / NN) - mean * mean;
    float sc = gm[c] * rsqrtf(var + BN_EPS);
    float sh = bt[c] - mean * sc;
    v[j] = sc * v[j] + sh;
  }
  *reinterpret_cast<f32x4*>(h + base) = v;
}

extern "C" void kernel_launch(void* const* d_in, const int* in_sizes, int n_in,
                              void* d_out, int out_size, void* d_ws, size_t ws_size,
                              hipStream_t stream) {
  const float* x    = (const float*)d_in[0];
  const float* ea   = (const float*)d_in[1];
  const float* w1g  = (const float*)d_in[2];
  const float* b1g  = (const float*)d_in[3];
  const float* w2g  = (const float*)d_in[4];
  const float* b2g  = (const float*)d_in[5];
  const float* bn1g = (const float*)d_in[6];
  const float* bn1b = (const float*)d_in[7];
  const float* ffw1 = (const float*)d_in[8];
  const float* ffb1 = (const float*)d_in[9];
  const float* ffw2 = (const float*)d_in[10];
  const float* ffb2 = (const float*)d_in[11];
  const float* bn2g = (const float*)d_in[12];
  const float* bn2b = (const float*)d_in[13];
  const int*   eidx = (const int*)d_in[14];
  float* out = (float*)d_out;

  char* ws = (char*)d_ws;
  int2* el2    = (int2*)(ws);                         // 12.8 MB
  int*  rs     = (int*)(ws + 12800000);               // (NN+1) ints
  int*  cursor = (int*)(ws + 13200128);               // NN ints
  int*  bsum   = (int*)(ws + 13600128);               // 391 ints
  int*  bpre   = (int*)(ws + 13601728);               // 391 ints
  float* stats = (float*)(ws + 13603328);             // 512 f32 (BN1 + BN2)
  float* par   = (float*)(ws + 13605376);             // 256 f32 (BN1 scale/shift)
  unsigned short* w1t  = (unsigned short*)(ws + 13607424);
  unsigned short* w2t  = w1t + 16384;
  unsigned short* fw1t = w2t + 16384;                 // 32768 elems
  unsigned short* fw2t = fw1t + 32768;                // 32768 elems
  unsigned short* xbf  = (unsigned short*)(ws + 13804032);  // 25.6 MB
  unsigned short* hbf  = (unsigned short*)(ws + 39404032);  // 25.6 MB (h0)

  hipMemsetAsync(rs, 0, (NN + 1) * 4, stream);
  hipMemsetAsync(stats, 0, 512 * 4, stream);

  k_prep_misc<<<6634, 256, 0, stream>>>(x, xbf, w1g, w2g, ffw1, ffw2,
                                        w1t, w2t, fw1t, fw2t);

  // build dst-sorted CSR with (edge,src) pairs
  k_hist<<<6250, 256, 0, stream>>>(eidx, rs);
  k_scan1<<<NB_SCAN, 256, 0, stream>>>(rs, bsum);
  k_scan2<<<1, 512, 0, stream>>>(bsum, bpre, rs);
  k_scan3<<<NB_SCAN, 256, 0, stream>>>(rs, bpre, cursor);
  k_scatter<<<6250, 256, 0, stream>>>(eidx, cursor, el2);

  // atomic-free edge aggregation, fused with h0 = x + agg (bf16 out)
  k_gather<<<12500, 256, 0, stream>>>(xbf, ea, rs, el2, hbf);

  k_mlp1<<<1563, 256, 0, stream>>>(hbf, w1t, b1g, w2t, b2g, x, out, stats);
  k_bnfin<<<1, 128, 0, stream>>>(stats, bn1g, bn1b, par);
  k_mlp2<<<1563, 256, 0, stream>>>(out, par, fw1t, ffb1, fw2t, ffb2, out, stats + 256);
  k_bnfinal<<<12500, 256, 0, stream>>>(out, stats + 256, bn2g, bn2b);
}